// Round 3
// baseline (247.977 us; speedup 1.0000x reference)
//
#include <hip/hip_runtime.h>

// Cost-volume / correlation layer, fp32.
// out[b, dy*9+dx, h, w] = (1/C) * sum_c first[b,c,h,w] * second[b,c,h+dy-4,w+dx-4]
// (zero outside bounds).  B=8, C=128, H=W=128, search_range=4 -> 81 offsets.
//
// Round-6: R5 confirmed the kernel is WAVE-STARVED, not pipeline-starved:
// total waves are fixed at 4608 (= B*MO*H*W/RW/64) vs 8192 slots, and the
// compiler caps in-flight loads regardless of register budget (VGPR=56).
// R4's C-split was the right idea but launch_bounds(512,8) clamped VGPR to
// 32 -> acc spilled to scratch (WRITE_SIZE 41->410MB).  This round: same
// split-C-by-2 structure (ty>=8 half does c in [64,128)) with
// __launch_bounds__(512,4) -> 128-VGPR cap.  Per-half body == R5's 3-set
// distance-2 pipeline, which compiles to 56 VGPR; 56<=64 still permits
// 8 waves/SIMD (4 blocks/CU, LDS 4*36KiB=144<=160KiB).  9216 waves -> full.

constexpr int B = 8, C = 128, H = 128, W = 128;
constexpr int RNG = 4, MO = 9;   // search range, max_offset = 2*RNG+1
constexpr int RW  = 4;           // pixels per thread along w
constexpr int TY  = 8;           // pixel rows per block
constexpr int C2  = C / 2;       // channels per half
constexpr int HWc = H * W;       // 16384, fits int

__global__ __launch_bounds__(512, 4) void corr_kernel(
    const float* __restrict__ first,
    const float* __restrict__ second,
    float* __restrict__ out)
{
    const int tx    = threadIdx.x;        // 0..31
    const int ty    = threadIdx.y;        // 0..15
    const int row   = ty & 7;             // pixel row within block
    const int chalf = ty >> 3;            // 0: c in [0,64)  1: c in [64,128)
    const int h  = blockIdx.x * TY + row; // 0..127
    const int dy = blockIdx.y;            // 0..8
    const int b  = blockIdx.z;
    const int w0 = tx * RW;               // 0..124

    __shared__ __align__(16) float red[TY][MO][32][RW];   // 36 KiB

    float acc[MO][RW];
#pragma unroll
    for (int dx = 0; dx < MO; ++dx)
#pragma unroll
        for (int p = 0; p < RW; ++p) acc[dx][p] = 0.0f;

    const int  srow_i = h + dy - RNG;
    const bool rvalid = (srow_i >= 0) && (srow_i < H);
    const int  srow_c = srow_i < 0 ? 0 : (srow_i >= H ? H - 1 : srow_i);

    // Column edges: tx==0 needs cols -4..-1 (zero), tx==31 needs 128..131.
    const bool ledge = (tx == 0);
    const bool redge = (tx == 31);
    const int off0 = ledge ? 0       : (w0 - 4);   // all 16B-aligned
    const int off2 = redge ? (W - 8) : (w0 + 4);

    if (rvalid) {
        const int cbase = (b * C + chalf * C2) * HWc;
        const float* fp  = first  + cbase + h * W + w0;
        const float* s0p = second + cbase + srow_c * W + off0;
        const float* s1p = second + cbase + srow_c * W + w0;
        const float* s2p = second + cbase + srow_c * W + off2;

        // ---- software pipeline: prefetch distance 2, 3 rotating sets ----
        float4 fA, a0A, a1A, a2A;
        float4 fB, a0B, a1B, a2B;
        float4 fC, a0C, a1C, a2C;

#define LOAD(SET)                                                           \
        {                                                                   \
            f##SET  = *(const float4*)(fp);                                 \
            a0##SET = *(const float4*)(s0p);                                \
            a1##SET = *(const float4*)(s1p);                                \
            a2##SET = *(const float4*)(s2p);                                \
            fp += HWc; s0p += HWc; s1p += HWc; s2p += HWc;                  \
        }

#define COMPUTE(SET)                                                        \
        {                                                                   \
            float4 z0 = a0##SET, z2 = a2##SET;                              \
            if (ledge) z0 = make_float4(0.f, 0.f, 0.f, 0.f);                \
            if (redge) z2 = make_float4(0.f, 0.f, 0.f, 0.f);                \
            float fv[RW] = {f##SET.x, f##SET.y, f##SET.z, f##SET.w};        \
            float s[12]  = {z0.x, z0.y, z0.z, z0.w,                         \
                            a1##SET.x, a1##SET.y, a1##SET.z, a1##SET.w,     \
                            z2.x, z2.y, z2.z, z2.w};                        \
            _Pragma("unroll")                                               \
            for (int dx = 0; dx < MO; ++dx)                                 \
                _Pragma("unroll")                                           \
                for (int p = 0; p < RW; ++p)                                \
                    acc[dx][p] += fv[p] * s[p + dx];                        \
        }

        LOAD(A)   // c = 0
        LOAD(B)   // c = 1
        for (int i = 0; i < (C2 - 4) / 3; ++i) {  // 20 iters: c = 3i..3i+2
            LOAD(C)      // c = 3i+2
            COMPUTE(A)   // c = 3i
            LOAD(A)      // c = 3i+3
            COMPUTE(B)   // c = 3i+1
            LOAD(B)      // c = 3i+4
            COMPUTE(C)   // c = 3i+2
        }
        // after loop: A=60, B=61; loads issued 0..61.  Remaining c=62,63.
        LOAD(C)      // 62
        COMPUTE(A)   // 60
        LOAD(A)      // 63
        COMPUTE(B)   // 61
        COMPUTE(C)   // 62
        COMPUTE(A)   // 63
#undef LOAD
#undef COMPUTE
    }

    // ---- combine the two C-halves through LDS ----
    if (chalf) {
#pragma unroll
        for (int dx = 0; dx < MO; ++dx)
            *(float4*)&red[row][dx][tx][0] =
                make_float4(acc[dx][0], acc[dx][1], acc[dx][2], acc[dx][3]);
    }
    __syncthreads();
    if (!chalf) {
        const float inv = 1.0f / (float)C;
        const size_t HW = (size_t)H * W;
        float* obase = out + ((size_t)b * (MO * MO) + (size_t)dy * MO) * HW
                           + (size_t)h * W + w0;
#pragma unroll
        for (int dx = 0; dx < MO; ++dx) {
            float4 r = *(const float4*)&red[row][dx][tx][0];
            float4 v = make_float4((acc[dx][0] + r.x) * inv,
                                   (acc[dx][1] + r.y) * inv,
                                   (acc[dx][2] + r.z) * inv,
                                   (acc[dx][3] + r.w) * inv);
            *(float4*)(obase + (size_t)dx * HW) = v;
        }
    }
}

extern "C" void kernel_launch(void* const* d_in, const int* in_sizes, int n_in,
                              void* d_out, int out_size, void* d_ws, size_t ws_size,
                              hipStream_t stream) {
    const float* first  = (const float*)d_in[0];
    const float* second = (const float*)d_in[1];
    float* out = (float*)d_out;

    dim3 grid(H / TY, MO, B);   // (16, 9, 8) = 1152 blocks
    dim3 block(32, 2 * TY);     // 512 threads = 8 waves
    corr_kernel<<<grid, block, 0, stream>>>(first, second, out);
}

// Round 4
// 185.144 us; speedup vs baseline: 1.3394x; 1.3394x over previous
//
#include <hip/hip_runtime.h>

// Cost-volume / correlation layer, fp32.
// out[b, dy*9+dx, h, w] = (1/C) * sum_c first[b,c,h,w] * second[b,c,h+dy-4,w+dx-4]
// (zero outside bounds).  B=8, C=128, H=W=128, search_range=4 -> 81 offsets.
//
// Round-7: structural rewrite.  R3-R6 proved the VMEM-latency path is stuck at
// ~130-140us: regalloc repeatedly refuses a deep register pipeline (VGPR
// clamped to 44/56/64, spills when pushed) and extra waves don't cover ~600cy
// L3 latency.  New structure:
//  - fold ALL 9 dy into one block: block = (32tx, 2h, 9dy) = 576 thr = 9 waves
//    (wave id == dy).  Grid (64,8) = 512 blocks = exactly 2/CU.
//    Global traffic per channel per block: 2 first rows + 10 second rows
//    = 6KB for 20736 FMAs (12x less cache-hierarchy pressure than R6).
//  - stage via global_load_lds (16B DMA, no VGPR round-trip), 4-buffer
//    distance-2 pipeline with counted s_waitcnt vmcnt(2) + raw s_barrier
//    (never drain vmcnt to 0 in the loop) -- latency hiding that the
//    register allocator cannot take away.
//  - compute reads from LDS: 4x ds_read_b128 + 36 FMA per channel per thread.
// Floors: VALU ~21us, LDS ~41us, HBM ~27us -> expect ~45-65us.

constexpr int B = 8, C = 128, H = 128, W = 128;
constexpr int RNG = 4, MO = 9;        // search range, max_offset
constexpr int RW  = 4;                // pixels per thread along w
constexpr int TH  = 2;                // h rows per block
constexpr int HWc = H * W;            // 16384
constexpr int SROWS = TH + 2 * RNG;   // 10 second rows per block
constexpr int SLAB  = (TH + SROWS) * W;   // 12*128 = 1536 floats = 6 KiB
constexpr int NBUF  = 4;              // distance-2 pipeline => 4 buffers

typedef float f32x4 __attribute__((ext_vector_type(4)));

__global__ __launch_bounds__(576)
__attribute__((amdgpu_waves_per_eu(2, 5)))   // don't let regalloc chase 8 w/EU
void corr_kernel(const float* __restrict__ first,
                 const float* __restrict__ second,
                 float* __restrict__ out)
{
    const int tx = threadIdx.x;           // 0..31
    const int hy = threadIdx.y;           // 0..1
    const int dz = threadIdx.z;           // 0..8  (== wave id: lane = tx+32*hy)
    const int h0 = blockIdx.x * TH;       // 0..126 (even)
    const int b  = blockIdx.y;
    const int w0 = tx * RW;               // 0..124
    const int lane = tx + 32 * hy;        // 0..63

    __shared__ __align__(16) float slab[NBUF][SLAB];

    // ---- staging roles (wave-uniform: one 1KiB DMA per wave per channel) ----
    // wave 0: first rows (h0, h0+1) -> slab rows 0..1
    // waves 1..5: second row-pair p = dz-1: rows (h0-4+2p, h0-4+2p+1)
    //             -> slab rows 2+2p .. 3+2p.  Pairs are even-aligned, so each
    //             pair is fully-valid or fully-invalid; invalid pairs are
    //             clamp-staged (finite data, never read).
    const float* gsrc = nullptr;
    int ldsoff = 0;
    if (dz == 0) {
        gsrc  = first + (size_t)b * C * HWc + h0 * W + lane * 4;
        ldsoff = 0;
    } else if (dz <= 5) {
        const int p  = dz - 1;
        const int r0 = h0 - RNG + 2 * p;                  // even, in [-4,130]
        const int cs = r0 < 0 ? 0 : (r0 > H - 2 ? H - 2 : r0);
        gsrc  = second + (size_t)b * C * HWc + cs * W + lane * 4;
        ldsoff = (TH + 2 * p) * W;
    }
    const bool do_stage = (dz <= 5);

    // ---- compute-side constants ----
    const int  srow   = h0 + hy + dz - RNG;
    const bool rvalid = (srow >= 0) && (srow < H);
    const bool ledge  = (tx == 0);
    const bool redge  = (tx == 31);
    const int off0  = ledge ? 0       : (w0 - 4);   // in-row, 16B aligned
    const int off2  = redge ? (W - 8) : (w0 + 4);
    const int fbase = hy * W + w0;
    const int sbase = (TH + hy + dz) * W;           // slab row 2+hy+dz

    float acc[MO][RW];
#pragma unroll
    for (int i = 0; i < MO; ++i)
#pragma unroll
        for (int p = 0; p < RW; ++p) acc[i][p] = 0.0f;

#define STAGE(k)                                                            \
    if (do_stage) {                                                         \
        __builtin_amdgcn_global_load_lds(                                   \
            (const __attribute__((address_space(1))) void*)                 \
                (gsrc + (size_t)(k) * HWc),                                 \
            (__attribute__((address_space(3))) void*)                       \
                (&slab[(k) & (NBUF - 1)][ldsoff]),                          \
            16, 0, 0);                                                      \
    }

    STAGE(0)
    STAGE(1)

    for (int k = 0; k < C; ++k) {
        if (k < C - 2) {
            STAGE(k + 2)                     // issue DMA for k+2 (buf (k+2)&3)
            asm volatile("s_waitcnt vmcnt(2)" ::: "memory");   // stage(k) done
        } else if (k == C - 2) {
            asm volatile("s_waitcnt vmcnt(1)" ::: "memory");
        } else {
            asm volatile("s_waitcnt vmcnt(0)" ::: "memory");
        }
        __builtin_amdgcn_s_barrier();        // publish buf k to all waves

        const float* sb = slab[k & (NBUF - 1)];
        f32x4 fv = *(const f32x4*)(sb + fbase);
        f32x4 a0 = *(const f32x4*)(sb + sbase + off0);
        f32x4 a1 = *(const f32x4*)(sb + sbase + w0);
        f32x4 a2 = *(const f32x4*)(sb + sbase + off2);
        if (ledge) a0 = (f32x4){0.f, 0.f, 0.f, 0.f};
        if (redge) a2 = (f32x4){0.f, 0.f, 0.f, 0.f};
        const float s[12] = {a0.x, a0.y, a0.z, a0.w,
                             a1.x, a1.y, a1.z, a1.w,
                             a2.x, a2.y, a2.z, a2.w};
        const float fvv[RW] = {fv.x, fv.y, fv.z, fv.w};
#pragma unroll
        for (int dx = 0; dx < MO; ++dx)
#pragma unroll
            for (int p = 0; p < RW; ++p)
                acc[dx][p] += fvv[p] * s[p + dx];

        // all ds_reads complete before we pass the next barrier (closes the
        // read-in-flight vs DMA-overwrite race); pin compiler ordering.
        asm volatile("s_waitcnt lgkmcnt(0)" ::: "memory");
        __builtin_amdgcn_sched_barrier(0);
    }
#undef STAGE

    // invalid srow => result must be 0 (acc holds finite garbage; *0 is safe)
    const float inv = rvalid ? (1.0f / (float)C) : 0.0f;
    float* obase = out + ((size_t)b * (MO * MO) + (size_t)dz * MO) * HWc
                       + (size_t)(h0 + hy) * W + w0;
#pragma unroll
    for (int dx = 0; dx < MO; ++dx) {
        f32x4 v = {acc[dx][0] * inv, acc[dx][1] * inv,
                   acc[dx][2] * inv, acc[dx][3] * inv};
        *(f32x4*)(obase + (size_t)dx * HWc) = v;
    }
}

extern "C" void kernel_launch(void* const* d_in, const int* in_sizes, int n_in,
                              void* d_out, int out_size, void* d_ws, size_t ws_size,
                              hipStream_t stream) {
    const float* first  = (const float*)d_in[0];
    const float* second = (const float*)d_in[1];
    float* out = (float*)d_out;

    dim3 grid(H / TH, B);       // (64, 8) = 512 blocks = exactly 2 per CU
    dim3 block(32, TH, MO);     // 576 threads = 9 waves, wave id == dy
    corr_kernel<<<grid, block, 0, stream>>>(first, second, out);
}